// Round 12
// baseline (608.488 us; speedup 1.0000x reference)
//
#include <hip/hip_runtime.h>
#include <math.h>

#define HMM_B 32
#define HMM_T 8192
#define HMM_K 64
#define L_EFF 512
#define L_WARM 384
#define C_CHUNKS (HMM_T / L_EFF)   /* 16 */
#define OBS_WIN 1024               /* >= L_WARM + L_EFF + pad; also >= bwd window */

#define LN2F 0.69314718055994531f
#define INV_LN2F 1.4426950408889634f
#define HALF_INV_LN2_SQRTF 0.8493218002880191f  /* sqrt(0.5/ln2) */
#define NEG_HALF_LOG_2PI 0.91893853320467274f

__device__ __forceinline__ float bcast0(float v) {
    return __int_as_float(__builtin_amdgcn_readfirstlane(__float_as_int(v)));
}
__device__ __forceinline__ float exp2_fast(float x) {
    float r; asm("v_exp_f32 %0, %1" : "=v"(r) : "v"(x)); return r;
}
__device__ __forceinline__ float log2_fast(float x) {
    float r; asm("v_log_f32 %0, %1" : "=v"(r) : "v"(x)); return r;
}
// v_permlane32_swap_b32 a(dst), b(src): exchanges one 32-lane half of dst with
// the complementary half of src. Direction (dst.row0<->src.row1 vs
// dst.row1<->src.row0) is probed at runtime -- see probe_flip().
__device__ __forceinline__ void pl32_swap(float& a, float& b) {
    asm("v_permlane32_swap_b32 %0, %1" : "+v"(a), "+v"(b));
}

// Probe the swap direction once (wave-uniform result, outside the hot loop).
// Input: 1.0 in lanes<32, 2.0 in lanes>=32, duplicated into both operands.
// After swap both operands are uniform; if the FIRST operand (dst) holds 2.0,
// dst received the high half (assumption A, flip=0); if 1.0, mirrored (flip=1).
__device__ __forceinline__ int probe_flip(int hs) {
    float pa = (float)(1 + hs);
    float pb = pa;
    pl32_swap(pa, pb);
    return (bcast0(pa) == 2.0f) ? 0 : 1;
}

// u_lane = sum_j A[lane][j] * w[j]; w in LDS (64 floats). Lane reads only its
// half (8 broadcast ds_read_b128: lanes<32 -> w[0:32), lanes>=32 -> w[32:64)),
// the other half arrives via permlane32_swap (independent VALU ops).
// 9 DS ops/step vs 17 for full-broadcast reads. With flip applied to the areg
// columns at load time, the FMA pairing is correct under either HW direction:
// the operand written with areg[32+..] is whichever register holds w[32+..].
__device__ __forceinline__ float matvec_swap(const float* __restrict__ areg,
                                             const float4* __restrict__ wbuf4,
                                             int hs /* lane>=32 */) {
    float4 c[8];
    const float4* base = wbuf4 + (hs << 3);
    #pragma unroll
    for (int k = 0; k < 8; ++k) c[k] = base[k];   // lanes<32: w[4k..4k+3]; lanes>=32: w[32+4k..]
    float a0 = 0.f, a1 = 0.f, a2 = 0.f, a3 = 0.f;
    #pragma unroll
    for (int k = 0; k < 8; ++k) {
        float xh = c[k].x, xl = c[k].x; pl32_swap(xh, xl);
        float yh = c[k].y, yl = c[k].y; pl32_swap(yh, yl);
        float zh = c[k].z, zl = c[k].z; pl32_swap(zh, zl);
        float wh = c[k].w, wl = c[k].w; pl32_swap(wh, wl);
        a0 = fmaf(areg[4 * k + 0], xl, a0);
        a1 = fmaf(areg[4 * k + 1], yl, a1);
        a2 = fmaf(areg[4 * k + 2], zl, a2);
        a3 = fmaf(areg[4 * k + 3], wl, a3);
        a0 = fmaf(areg[32 + 4 * k + 0], xh, a0);
        a1 = fmaf(areg[32 + 4 * k + 1], yh, a1);
        a2 = fmaf(areg[32 + 4 * k + 2], zh, a2);
        a3 = fmaf(areg[32 + 4 * k + 3], wh, a3);
    }
    return (a0 + a1) + (a2 + a3);
}

// areg load with direction fix folded into the COLUMN index (global address,
// register indices stay compile-time).
__device__ __forceinline__ void load_areg(const float* __restrict__ transfer,
                                          int lane, int flip, float* areg) {
    const int xorm = flip ? 32 : 0;
    #pragma unroll
    for (int j = 0; j < HMM_K; ++j)
        areg[j] = transfer[lane * HMM_K + (j ^ xorm)];
}

// one fwd step: v=f_t -> f_{t+1}; e2c holds emission(t+1); prefetches emission(t+2)
#define FWD_STEP { \
    float d_ = fminf(v - bcast0(v), 100.0f); \
    float w_ = exp2_fast(d_); \
    *wbs = w_; \
    __builtin_amdgcn_wave_barrier(); \
    float u_ = matvec_swap(areg, wbuf4, hs); \
    __builtin_amdgcn_wave_barrier(); \
    float xn_ = ow[t + 1]; \
    float zn_ = (xn_ - mean_k) * inv_std2; \
    float e2n_ = fmaf(-zn_, zn_, ce2); \
    v = e2c + log2_fast(u_); \
    e2c = e2n_; }

// one bwd step: v=b_t -> b_{t-1}; e2c holds emission(t); prefetches emission(t-1)
#define BWD_STEP { \
    float tmp_ = v + e2c; \
    float d_ = fminf(tmp_ - bcast0(tmp_), 100.0f); \
    float w_ = exp2_fast(d_); \
    *wbs = w_; \
    __builtin_amdgcn_wave_barrier(); \
    float u_ = matvec_swap(areg, wbuf4, hs); \
    __builtin_amdgcn_wave_barrier(); \
    float xn_ = ow[t - 1]; \
    float zn_ = (xn_ - mean_k) * inv_std2; \
    float e2n_ = fmaf(-zn_, zn_, ce2); \
    v = log2_fast(u_); \
    e2c = e2n_; }

// Chunked recurrences with warmup. Blocks [0, B*C): fwd chunk (b = blk>>4, c = blk&15).
// Blocks [B*C, 2*B*C): bwd chunk. Warm chunks start from a uniform vector L_WARM
// steps outside their window (L_WARM <= L_EFF keeps all indices in [0, T)).
// Hilbert contraction of A converges the direction; the scale offset cancels
// in the final per-row logsumexp.
__global__ void __launch_bounds__(64, 1)
hmm_recur_chunk(const float* __restrict__ obvs,
                const float* __restrict__ log_init,
                const float* __restrict__ transfer,
                const float* __restrict__ means,
                const float* __restrict__ log_stds,
                float* __restrict__ f_out,
                float* __restrict__ b_out)
{
    __shared__ float4 wbuf4[16];
    __shared__ float obs_lds[OBS_WIN];
    const int lane = threadIdx.x;
    const int hs = lane >> 5;
    int blk = blockIdx.x;
    const bool is_fwd = blk < HMM_B * C_CHUNKS;
    if (!is_fwd) blk -= HMM_B * C_CHUNKS;
    const int b  = blk >> 4;
    const int c  = blk & (C_CHUNKS - 1);
    const int t0 = c * L_EFF;
    const int tE = t0 + L_EFF;

    const float mean_k   = means[lane];
    const float ls       = log_stds[lane];
    const float inv_std2 = __expf(-ls) * HALF_INV_LN2_SQRTF; // e2 = -((x-m)*is2)^2 + ce2 (log2 units)
    const float ce2      = (-ls - NEG_HALF_LOG_2PI) * INV_LN2F;
    const float li2      = log_init[lane] * INV_LN2F;

    const int flip = probe_flip(hs);
    float areg[HMM_K];
    load_areg(transfer, lane, flip, areg);

    const float* __restrict__ orow = obvs + (size_t)b * HMM_T;
    const int w_lo = is_fwd ? ((c == 0) ? 0 : ((t0 - L_WARM) & ~3)) : t0;
    int nfl = HMM_T - w_lo; if (nfl > OBS_WIN) nfl = OBS_WIN;
    {
        const float4* o4 = (const float4*)(orow + w_lo);
        float4* l4 = (float4*)obs_lds;
        for (int i = lane; i < (nfl >> 2); i += 64) l4[i] = o4[i];
    }
    __syncthreads();                       // single wave -> waitcnt only
    const float* ow = obs_lds - w_lo;      // ow[t] valid for t in [w_lo, w_lo+nfl)
    float* wbs = ((float*)wbuf4) + lane;

    if (is_fwd) {
        const int t_s = (c == 0) ? 0 : (t0 - L_WARM);
        float x0 = ow[t_s];
        float z0 = (x0 - mean_k) * inv_std2;
        float v  = fmaf(-z0, z0, ce2) + ((c == 0) ? li2 : 0.0f);  // uniform prior for warm chunks
        float* po;
        if (c == 0) {
            po = f_out + ((size_t)b * HMM_T + 0) * HMM_K + lane;
            *po = v;                       // row 0 stored
        } else {
            po = f_out + ((size_t)b * HMM_T + (t0 - 1)) * HMM_K + lane;  // not written
        }
        float x1 = ow[t_s + 1];
        float z1 = (x1 - mean_k) * inv_std2;
        float e2c = fmaf(-z1, z1, ce2);
        int t = t_s + 1;
        for (; t < t0; ++t) {              // warmup (empty for c==0)
            FWD_STEP
        }
        for (; t < tE; ++t) {              // stored region
            FWD_STEP
            po += HMM_K; *po = v;
        }
    } else {
        const bool last = (c == C_CHUNKS - 1);
        int t = last ? (HMM_T - 1) : (tE - 1 + L_WARM);   // <= T-1 since L_WARM <= L_EFF
        float v;
        float* po;
        if (last) {
            v = li2;                       // b_{T-1} = log_initial_probs (exact)
            po = b_out + ((size_t)b * HMM_T + (HMM_T - 1)) * HMM_K + lane;
            *po = v;
        } else {
            v = 0.0f;                      // uniform init at warmup start
            po = b_out + ((size_t)b * HMM_T + tE) * HMM_K + lane;  // one row above first store
        }
        float xs = ow[t];
        float zs = (xs - mean_k) * inv_std2;
        float e2c = fmaf(-zs, zs, ce2);
        for (; t > tE; --t) {              // warmup (empty for last chunk)
            BWD_STEP
        }
        for (; t > t0; --t) {              // stored region: writes rows tE-1 .. t0
            BWD_STEP
            po -= HMM_K; *po = v;
        }
    }
}

// gamma = ln2 * (g2 - m - log2(sum exp2(g2 - m))), g2 = f2+b2 (log2 domain, offsets cancel)
__global__ void __launch_bounds__(256)
hmm_combine(const float* __restrict__ fbuf,
            const float* __restrict__ bbuf,
            float* __restrict__ out)
{
    const size_t row = (size_t)blockIdx.x * 4 + (threadIdx.x >> 6);
    const int lane = threadIdx.x & 63;
    const size_t idx = row * HMM_K + lane;
    float g = fbuf[idx] + bbuf[idx];
    float m = g;
    #pragma unroll
    for (int off = 32; off > 0; off >>= 1) m = fmaxf(m, __shfl_xor(m, off));
    float e = exp2_fast(g - m);
    float s = e;
    #pragma unroll
    for (int off = 32; off > 0; off >>= 1) s += __shfl_xor(s, off);
    out[idx] = LN2F * ((g - m) - log2_fast(s));
}

// ---------- fallback path (ws too small): full-T serial fwd, then bwd fused w/ combine ----------
__global__ void __launch_bounds__(64, 1)
hmm_fwd_single(const float* __restrict__ obvs,
               const float* __restrict__ log_init,
               const float* __restrict__ transfer,
               const float* __restrict__ means,
               const float* __restrict__ log_stds,
               float* __restrict__ f_out)
{
    __shared__ float4 wbuf4[16];
    __shared__ float obs_lds_full[HMM_T + 4];
    const int lane = threadIdx.x;
    const int hs = lane >> 5;
    const int b = blockIdx.x;
    const float mean_k   = means[lane];
    const float ls       = log_stds[lane];
    const float inv_std2 = __expf(-ls) * HALF_INV_LN2_SQRTF;
    const float ce2      = (-ls - NEG_HALF_LOG_2PI) * INV_LN2F;
    const float li2      = log_init[lane] * INV_LN2F;
    const int flip = probe_flip(hs);
    float areg[HMM_K];
    load_areg(transfer, lane, flip, areg);
    const float* __restrict__ orow = obvs + (size_t)b * HMM_T;
    {
        const float4* o4 = (const float4*)orow;
        float4* l4 = (float4*)obs_lds_full;
        #pragma unroll 4
        for (int i = lane; i < HMM_T / 4; i += 64) l4[i] = o4[i];
    }
    __syncthreads();
    const float* ow = obs_lds_full;
    float* wbs = ((float*)wbuf4) + lane;
    float x0 = ow[0];
    float z0 = (x0 - mean_k) * inv_std2;
    float v  = fmaf(-z0, z0, ce2) + li2;
    float* po = f_out + (size_t)b * HMM_T * HMM_K + lane;
    *po = v;
    float x1 = ow[1];
    float z1 = (x1 - mean_k) * inv_std2;
    float e2c = fmaf(-z1, z1, ce2);
    for (int t = 1; t < HMM_T; ++t) {
        FWD_STEP
        po += HMM_K; *po = v;
    }
}

__global__ void __launch_bounds__(64, 1)
hmm_bwd_combine(const float* __restrict__ obvs,
                const float* __restrict__ log_init,
                const float* __restrict__ transfer,
                const float* __restrict__ means,
                const float* __restrict__ log_stds,
                float* __restrict__ fout)
{
    __shared__ float4 wbuf4[16];
    __shared__ float obs_lds_full[HMM_T + 4];
    const int lane = threadIdx.x;
    const int hs = lane >> 5;
    const int b = blockIdx.x;
    const float mean_k   = means[lane];
    const float ls       = log_stds[lane];
    const float inv_std2 = __expf(-ls) * HALF_INV_LN2_SQRTF;
    const float ce2      = (-ls - NEG_HALF_LOG_2PI) * INV_LN2F;
    const float li2      = log_init[lane] * INV_LN2F;
    const int flip = probe_flip(hs);
    float areg[HMM_K];
    load_areg(transfer, lane, flip, areg);
    const float* __restrict__ orow = obvs + (size_t)b * HMM_T;
    {
        const float4* o4 = (const float4*)orow;
        float4* l4 = (float4*)obs_lds_full;
        #pragma unroll 4
        for (int i = lane; i < HMM_T / 4; i += 64) l4[i] = o4[i];
    }
    __syncthreads();
    const float* ow = obs_lds_full;
    float* wbs = ((float*)wbuf4) + lane;
    float bb = li2;
    for (int t = HMM_T - 1; t >= 0; --t) {
        const size_t base = ((size_t)b * HMM_T + t) * HMM_K;
        float g = fout[base + lane] + bb;
        float m = g;
        #pragma unroll
        for (int off = 32; off > 0; off >>= 1) m = fmaxf(m, __shfl_xor(m, off));
        float e = exp2_fast(g - m);
        float s = e;
        #pragma unroll
        for (int off = 32; off > 0; off >>= 1) s += __shfl_xor(s, off);
        fout[base + lane] = LN2F * ((g - m) - log2_fast(s));
        if (t > 0) {
            float xt = ow[t];
            float zt = (xt - mean_k) * inv_std2;
            float tmp = bb + fmaf(-zt, zt, ce2);
            float d = fminf(tmp - bcast0(tmp), 100.0f);
            float w = exp2_fast(d);
            *wbs = w;
            __builtin_amdgcn_wave_barrier();
            float u = matvec_swap(areg, wbuf4, hs);
            __builtin_amdgcn_wave_barrier();
            bb = log2_fast(u);
        }
    }
}

extern "C" void kernel_launch(void* const* d_in, const int* in_sizes, int n_in,
                              void* d_out, int out_size, void* d_ws, size_t ws_size,
                              hipStream_t stream)
{
    const float* obvs     = (const float*)d_in[0];
    const float* log_init = (const float*)d_in[1];
    const float* transfer = (const float*)d_in[2];
    const float* means    = (const float*)d_in[3];
    const float* log_stds = (const float*)d_in[4];
    float* out = (float*)d_out;

    const size_t need = (size_t)HMM_B * HMM_T * HMM_K * sizeof(float);
    if (ws_size >= need) {
        float* bws = (float*)d_ws;
        hipLaunchKernelGGL(hmm_recur_chunk, dim3(2 * HMM_B * C_CHUNKS), dim3(HMM_K), 0, stream,
                           obvs, log_init, transfer, means, log_stds, out, bws);
        hipLaunchKernelGGL(hmm_combine, dim3(HMM_B * HMM_T / 4), dim3(256), 0, stream,
                           out, bws, out);
    } else {
        hipLaunchKernelGGL(hmm_fwd_single, dim3(HMM_B), dim3(HMM_K), 0, stream,
                           obvs, log_init, transfer, means, log_stds, out);
        hipLaunchKernelGGL(hmm_bwd_combine, dim3(HMM_B), dim3(HMM_K), 0, stream,
                           obvs, log_init, transfer, means, log_stds, out);
    }
}

// Round 14
// 325.869 us; speedup vs baseline: 1.8673x; 1.8673x over previous
//
#include <hip/hip_runtime.h>
#include <math.h>

#define HMM_B 32
#define HMM_T 8192
#define HMM_K 64
#define L_EFF 512
#define L_WARM 384
#define C_CHUNKS (HMM_T / L_EFF)   /* 16 */
#define OBS_WIN 1024               /* >= L_WARM + L_EFF + pad */

#define LN2F 0.69314718055994531f
#define INV_LN2F 1.4426950408889634f
#define HALF_INV_LN2_SQRTF 0.8493218002880191f  /* sqrt(0.5/ln2) */
#define NEG_HALF_LOG_2PI 0.91893853320467274f

__device__ __forceinline__ float bcast0(float v) {
    return __int_as_float(__builtin_amdgcn_readfirstlane(__float_as_int(v)));
}
__device__ __forceinline__ float exp2_fast(float x) {
    float r; asm("v_exp_f32 %0, %1" : "=v"(r) : "v"(x)); return r;
}
__device__ __forceinline__ float log2_fast(float x) {
    float r; asm("v_log_f32 %0, %1" : "=v"(r) : "v"(x)); return r;
}

// Split-row matvec; cross-half exchange via ds_bpermute (validated round 5).
// Lane l reads its half of w (8 broadcast ds_read_b128), computes:
//   own   = sum_{j<32} A[l   ][jbase+j] * w[jbase+j]
//   cross = sum_{j<32} A[l^32][jbase+j] * w[jbase+j]
// One ds_bpermute pulls cross from lane l^32. u_l = own + recv.
// 10 DS ops/step vs 17 for the full-broadcast matvec.
__device__ __forceinline__ float matvec_split(const float* __restrict__ aown,
                                              const float* __restrict__ across,
                                              const float4* __restrict__ wbuf4,
                                              int hs, int bpaddr /* (lane^32)<<2 */) {
    float4 c[8];
    const float4* base = wbuf4 + (hs << 3);
    #pragma unroll
    for (int k = 0; k < 8; ++k) c[k] = base[k];
    float o0 = 0.f, o1 = 0.f, o2 = 0.f, o3 = 0.f;
    float x0 = 0.f, x1 = 0.f, x2 = 0.f, x3 = 0.f;
    #pragma unroll
    for (int k = 0; k < 8; ++k) {
        o0 = fmaf(aown[4 * k + 0], c[k].x, o0);
        o1 = fmaf(aown[4 * k + 1], c[k].y, o1);
        o2 = fmaf(aown[4 * k + 2], c[k].z, o2);
        o3 = fmaf(aown[4 * k + 3], c[k].w, o3);
        x0 = fmaf(across[4 * k + 0], c[k].x, x0);
        x1 = fmaf(across[4 * k + 1], c[k].y, x1);
        x2 = fmaf(across[4 * k + 2], c[k].z, x2);
        x3 = fmaf(across[4 * k + 3], c[k].w, x3);
    }
    float own = (o0 + o1) + (o2 + o3);
    float D   = (x0 + x1) + (x2 + x3);
    float recv = __int_as_float(__builtin_amdgcn_ds_bpermute(bpaddr, __float_as_int(D)));
    return own + recv;
}

// aown[j] = A[l][jbase+j], across[j] = A[l^32][jbase+j]  (jbase = lane&32)
__device__ __forceinline__ void load_aregs(const float* __restrict__ transfer,
                                           int lane, float* aown, float* across) {
    const int jbase = (lane & 32);
    #pragma unroll
    for (int j = 0; j < 32; ++j) {
        aown[j]   = transfer[lane * HMM_K + jbase + j];
        across[j] = transfer[(lane ^ 32) * HMM_K + jbase + j];
    }
}

// one fwd step: v=f_t -> f_{t+1}; e2c holds emission(t+1); prefetches emission(t+2)
#define FWD_STEP { \
    float d_ = fminf(v - bcast0(v), 100.0f); \
    float w_ = exp2_fast(d_); \
    *wbs = w_; \
    __builtin_amdgcn_wave_barrier(); \
    float u_ = matvec_split(aown, across, wbuf4, hs, bpaddr); \
    __builtin_amdgcn_wave_barrier(); \
    float xn_ = ow[t + 1]; \
    float zn_ = (xn_ - mean_k) * inv_std2; \
    float e2n_ = fmaf(-zn_, zn_, ce2); \
    v = e2c + log2_fast(u_); \
    e2c = e2n_; }

// one bwd step: v=b_t -> b_{t-1}; e2c holds emission(t); prefetches emission(t-1)
#define BWD_STEP { \
    float tmp_ = v + e2c; \
    float d_ = fminf(tmp_ - bcast0(tmp_), 100.0f); \
    float w_ = exp2_fast(d_); \
    *wbs = w_; \
    __builtin_amdgcn_wave_barrier(); \
    float u_ = matvec_split(aown, across, wbuf4, hs, bpaddr); \
    __builtin_amdgcn_wave_barrier(); \
    float xn_ = ow[t - 1]; \
    float zn_ = (xn_ - mean_k) * inv_std2; \
    float e2n_ = fmaf(-zn_, zn_, ce2); \
    v = log2_fast(u_); \
    e2c = e2n_; }

// Chunked recurrences with warmup (geometry identical to rounds 6/8/12 — known-good).
__global__ void __launch_bounds__(64, 1)
hmm_recur_chunk(const float* __restrict__ obvs,
                const float* __restrict__ log_init,
                const float* __restrict__ transfer,
                const float* __restrict__ means,
                const float* __restrict__ log_stds,
                float* __restrict__ f_out,
                float* __restrict__ b_out)
{
    __shared__ float4 wbuf4[16];
    __shared__ float obs_lds[OBS_WIN];
    const int lane = threadIdx.x;
    const int hs = lane >> 5;
    const int bpaddr = (lane ^ 32) << 2;
    int blk = blockIdx.x;
    const bool is_fwd = blk < HMM_B * C_CHUNKS;
    if (!is_fwd) blk -= HMM_B * C_CHUNKS;
    const int b  = blk >> 4;
    const int c  = blk & (C_CHUNKS - 1);
    const int t0 = c * L_EFF;
    const int tE = t0 + L_EFF;

    const float mean_k   = means[lane];
    const float ls       = log_stds[lane];
    const float inv_std2 = __expf(-ls) * HALF_INV_LN2_SQRTF; // e2 = -((x-m)*is2)^2 + ce2 (log2 units)
    const float ce2      = (-ls - NEG_HALF_LOG_2PI) * INV_LN2F;
    const float li2      = log_init[lane] * INV_LN2F;

    float aown[32], across[32];
    load_aregs(transfer, lane, aown, across);

    const float* __restrict__ orow = obvs + (size_t)b * HMM_T;
    const int w_lo = is_fwd ? ((c == 0) ? 0 : ((t0 - L_WARM) & ~3)) : t0;
    int nfl = HMM_T - w_lo; if (nfl > OBS_WIN) nfl = OBS_WIN;
    {
        const float4* o4 = (const float4*)(orow + w_lo);
        float4* l4 = (float4*)obs_lds;
        for (int i = lane; i < (nfl >> 2); i += 64) l4[i] = o4[i];
    }
    __syncthreads();                       // single wave -> waitcnt only
    const float* ow = obs_lds - w_lo;      // ow[t] valid for t in [w_lo, w_lo+nfl)
    float* wbs = ((float*)wbuf4) + lane;

    if (is_fwd) {
        const int t_s = (c == 0) ? 0 : (t0 - L_WARM);
        float x0 = ow[t_s];
        float z0 = (x0 - mean_k) * inv_std2;
        float v  = fmaf(-z0, z0, ce2) + ((c == 0) ? li2 : 0.0f);  // uniform prior for warm chunks
        float* po;
        if (c == 0) {
            po = f_out + ((size_t)b * HMM_T + 0) * HMM_K + lane;
            *po = v;                       // row 0 stored
        } else {
            po = f_out + ((size_t)b * HMM_T + (t0 - 1)) * HMM_K + lane;  // not written
        }
        float x1 = ow[t_s + 1];
        float z1 = (x1 - mean_k) * inv_std2;
        float e2c = fmaf(-z1, z1, ce2);
        int t = t_s + 1;
        for (; t < t0; ++t) {              // warmup (empty for c==0)
            FWD_STEP
        }
        for (; t < tE; ++t) {              // stored region
            FWD_STEP
            po += HMM_K; *po = v;
        }
    } else {
        const bool last = (c == C_CHUNKS - 1);
        int t = last ? (HMM_T - 1) : (tE - 1 + L_WARM);   // <= T-1 since L_WARM <= L_EFF
        float v;
        float* po;
        if (last) {
            v = li2;                       // b_{T-1} = log_initial_probs (exact)
            po = b_out + ((size_t)b * HMM_T + (HMM_T - 1)) * HMM_K + lane;
            *po = v;
        } else {
            v = 0.0f;                      // uniform init at warmup start
            po = b_out + ((size_t)b * HMM_T + tE) * HMM_K + lane;  // one row above first store
        }
        float xs = ow[t];
        float zs = (xs - mean_k) * inv_std2;
        float e2c = fmaf(-zs, zs, ce2);
        for (; t > tE; --t) {              // warmup (empty for last chunk)
            BWD_STEP
        }
        for (; t > t0; --t) {              // stored region: writes rows tE-1 .. t0
            BWD_STEP
            po -= HMM_K; *po = v;
        }
    }
}

// gamma = ln2 * (g2 - m - log2(sum exp2(g2 - m))), g2 = f2+b2 (log2 domain, offsets cancel)
__global__ void __launch_bounds__(256)
hmm_combine(const float* __restrict__ fbuf,
            const float* __restrict__ bbuf,
            float* __restrict__ out)
{
    const size_t row = (size_t)blockIdx.x * 4 + (threadIdx.x >> 6);
    const int lane = threadIdx.x & 63;
    const size_t idx = row * HMM_K + lane;
    float g = fbuf[idx] + bbuf[idx];
    float m = g;
    #pragma unroll
    for (int off = 32; off > 0; off >>= 1) m = fmaxf(m, __shfl_xor(m, off));
    float e = exp2_fast(g - m);
    float s = e;
    #pragma unroll
    for (int off = 32; off > 0; off >>= 1) s += __shfl_xor(s, off);
    out[idx] = LN2F * ((g - m) - log2_fast(s));
}

// ---------- fallback path (ws too small): full-T serial fwd, then bwd fused w/ combine ----------
__global__ void __launch_bounds__(64, 1)
hmm_fwd_single(const float* __restrict__ obvs,
               const float* __restrict__ log_init,
               const float* __restrict__ transfer,
               const float* __restrict__ means,
               const float* __restrict__ log_stds,
               float* __restrict__ f_out)
{
    __shared__ float4 wbuf4[16];
    __shared__ float obs_lds_full[HMM_T + 4];
    const int lane = threadIdx.x;
    const int hs = lane >> 5;
    const int bpaddr = (lane ^ 32) << 2;
    const int b = blockIdx.x;
    const float mean_k   = means[lane];
    const float ls       = log_stds[lane];
    const float inv_std2 = __expf(-ls) * HALF_INV_LN2_SQRTF;
    const float ce2      = (-ls - NEG_HALF_LOG_2PI) * INV_LN2F;
    const float li2      = log_init[lane] * INV_LN2F;
    float aown[32], across[32];
    load_aregs(transfer, lane, aown, across);
    const float* __restrict__ orow = obvs + (size_t)b * HMM_T;
    {
        const float4* o4 = (const float4*)orow;
        float4* l4 = (float4*)obs_lds_full;
        #pragma unroll 4
        for (int i = lane; i < HMM_T / 4; i += 64) l4[i] = o4[i];
    }
    __syncthreads();
    const float* ow = obs_lds_full;
    float* wbs = ((float*)wbuf4) + lane;
    float x0 = ow[0];
    float z0 = (x0 - mean_k) * inv_std2;
    float v  = fmaf(-z0, z0, ce2) + li2;
    float* po = f_out + (size_t)b * HMM_T * HMM_K + lane;
    *po = v;
    float x1 = ow[1];
    float z1 = (x1 - mean_k) * inv_std2;
    float e2c = fmaf(-z1, z1, ce2);
    for (int t = 1; t < HMM_T; ++t) {
        FWD_STEP
        po += HMM_K; *po = v;
    }
}

__global__ void __launch_bounds__(64, 1)
hmm_bwd_combine(const float* __restrict__ obvs,
                const float* __restrict__ log_init,
                const float* __restrict__ transfer,
                const float* __restrict__ means,
                const float* __restrict__ log_stds,
                float* __restrict__ fout)
{
    __shared__ float4 wbuf4[16];
    __shared__ float obs_lds_full[HMM_T + 4];
    const int lane = threadIdx.x;
    const int hs = lane >> 5;
    const int bpaddr = (lane ^ 32) << 2;
    const int b = blockIdx.x;
    const float mean_k   = means[lane];
    const float ls       = log_stds[lane];
    const float inv_std2 = __expf(-ls) * HALF_INV_LN2_SQRTF;
    const float ce2      = (-ls - NEG_HALF_LOG_2PI) * INV_LN2F;
    const float li2      = log_init[lane] * INV_LN2F;
    float aown[32], across[32];
    load_aregs(transfer, lane, aown, across);
    const float* __restrict__ orow = obvs + (size_t)b * HMM_T;
    {
        const float4* o4 = (const float4*)orow;
        float4* l4 = (float4*)obs_lds_full;
        #pragma unroll 4
        for (int i = lane; i < HMM_T / 4; i += 64) l4[i] = o4[i];
    }
    __syncthreads();
    const float* ow = obs_lds_full;
    float* wbs = ((float*)wbuf4) + lane;
    float bb = li2;
    for (int t = HMM_T - 1; t >= 0; --t) {
        const size_t base = ((size_t)b * HMM_T + t) * HMM_K;
        float g = fout[base + lane] + bb;
        float m = g;
        #pragma unroll
        for (int off = 32; off > 0; off >>= 1) m = fmaxf(m, __shfl_xor(m, off));
        float e = exp2_fast(g - m);
        float s = e;
        #pragma unroll
        for (int off = 32; off > 0; off >>= 1) s += __shfl_xor(s, off);
        fout[base + lane] = LN2F * ((g - m) - log2_fast(s));
        if (t > 0) {
            float xt = ow[t];
            float zt = (xt - mean_k) * inv_std2;
            float tmp = bb + fmaf(-zt, zt, ce2);
            float d = fminf(tmp - bcast0(tmp), 100.0f);
            float w = exp2_fast(d);
            *wbs = w;
            __builtin_amdgcn_wave_barrier();
            float u = matvec_split(aown, across, wbuf4, hs, bpaddr);
            __builtin_amdgcn_wave_barrier();
            bb = log2_fast(u);
        }
    }
}

extern "C" void kernel_launch(void* const* d_in, const int* in_sizes, int n_in,
                              void* d_out, int out_size, void* d_ws, size_t ws_size,
                              hipStream_t stream)
{
    const float* obvs     = (const float*)d_in[0];
    const float* log_init = (const float*)d_in[1];
    const float* transfer = (const float*)d_in[2];
    const float* means    = (const float*)d_in[3];
    const float* log_stds = (const float*)d_in[4];
    float* out = (float*)d_out;

    const size_t need = (size_t)HMM_B * HMM_T * HMM_K * sizeof(float);
    if (ws_size >= need) {
        float* bws = (float*)d_ws;
        hipLaunchKernelGGL(hmm_recur_chunk, dim3(2 * HMM_B * C_CHUNKS), dim3(HMM_K), 0, stream,
                           obvs, log_init, transfer, means, log_stds, out, bws);
        hipLaunchKernelGGL(hmm_combine, dim3(HMM_B * HMM_T / 4), dim3(256), 0, stream,
                           out, bws, out);
    } else {
        hipLaunchKernelGGL(hmm_fwd_single, dim3(HMM_B), dim3(HMM_K), 0, stream,
                           obvs, log_init, transfer, means, log_stds, out);
        hipLaunchKernelGGL(hmm_bwd_combine, dim3(HMM_B), dim3(HMM_K), 0, stream,
                           obvs, log_init, transfer, means, log_stds, out);
    }
}